// Round 5
// baseline (2684.301 us; speedup 1.0000x reference)
//
#include <hip/hip_runtime.h>
#include <math.h>

#define N_NODES 50000
#define N_EDGES 800000
#define N_GRAPH 1024
#define CDIM 128
#define FINDIM 16
#define NL 3
#define WTP 132   // WT row pitch in ushorts: bank=(2m+4q)%32 -> 4-way via b64 reads

using short8  = __attribute__((ext_vector_type(8))) short;
using floatx4 = __attribute__((ext_vector_type(4))) float;

__device__ __forceinline__ float sspf(float x) {
    return fmaxf(x, 0.0f) + __logf(1.0f + __expf(-fabsf(x))) - 0.6931471805599453f;
}

__device__ __forceinline__ unsigned short f2bf(float f) {
    unsigned int u = __float_as_uint(f);
    u = u + 0x7FFFu + ((u >> 16) & 1u);   // RNE
    return (unsigned short)(u >> 16);
}

__device__ __forceinline__ float bf2f(unsigned short h) {
    return __uint_as_float((unsigned int)h << 16);
}

// load a B fragment from WT (pitch WTP) as 2x ds_read_b64 (8B-aligned, 4-way banks)
__device__ __forceinline__ short8 ldfrag(const unsigned short* WT, int c, int k0) {
    const uint2* p = (const uint2*)(WT + c * WTP + k0);
    short8 r;
    *(uint2*)&r       = p[0];
    *((uint2*)&r + 1) = p[1];
    return r;
}

// ---------------------------------------------------------------- embedding (+ BN stats)
__global__ void k_fuse(const float* __restrict__ Wl1, const float* __restrict__ bl1,
                       const float* __restrict__ Wl2, const float* __restrict__ bl2,
                       float* __restrict__ Wf, float* __restrict__ bfv) {
    for (int o = threadIdx.x; o < FINDIM * CDIM + CDIM; o += 256) {
        if (o < FINDIM * CDIM) {
            int f = o >> 7, c = o & 127;
            float s = 0.f;
            for (int k = 0; k < CDIM; ++k) s += Wl1[f * CDIM + k] * Wl2[k * CDIM + c];
            Wf[o] = s;
        } else {
            int c = o - FINDIM * CDIM;
            float s = bl2[c];
            for (int k = 0; k < CDIM; ++k) s += bl1[k] * Wl2[k * CDIM + c];
            bfv[c] = s;
        }
    }
}

__global__ void k_embed_bn(const float* __restrict__ x, const float* __restrict__ Wf,
                           const float* __restrict__ bfv, float* __restrict__ h,
                           float* __restrict__ bnsum) {
    __shared__ float wfs[FINDIM * CDIM];
    __shared__ float bfs[CDIM];
    __shared__ float sd[512];
    for (int o = threadIdx.x; o < FINDIM * CDIM; o += 256) wfs[o] = Wf[o];
    if (threadIdx.x < CDIM) bfs[threadIdx.x] = bfv[threadIdx.x];
    __syncthreads();
    int c = threadIdx.x & 127;
    int half = threadIdx.x >> 7;
    float s1 = 0.f, s2 = 0.f;
    for (int base = blockIdx.x * 2; base < N_NODES; base += gridDim.x * 2) {
        int n = base + half;
        if (n < N_NODES) {
            float s = bfs[c];
            const float* xp = x + (size_t)n * FINDIM;
#pragma unroll
            for (int f = 0; f < FINDIM; ++f) s += xp[f] * wfs[f * CDIM + c];
            h[(size_t)n * CDIM + c] = s;
            s1 += s; s2 += s * s;
        }
    }
    sd[threadIdx.x] = s1; sd[256 + threadIdx.x] = s2;
    __syncthreads();
    if (threadIdx.x < 128) {
        atomicAdd(&bnsum[threadIdx.x], sd[threadIdx.x] + sd[threadIdx.x + 128]);
        atomicAdd(&bnsum[128 + threadIdx.x], sd[256 + threadIdx.x] + sd[256 + threadIdx.x + 128]);
    }
}

// BN apply, writes f32 h and bf16 shadow hb
__global__ void k_bnapply(float* __restrict__ h, unsigned short* __restrict__ hb,
                          const float* __restrict__ bnsum,
                          const float* __restrict__ g, const float* __restrict__ b) {
    const float invN = 1.0f / (float)N_NODES;
    for (size_t i = (size_t)blockIdx.x * 256 + threadIdx.x; i < (size_t)N_NODES * CDIM;
         i += (size_t)gridDim.x * 256) {
        int c = (int)(i & 127);
        float mu  = bnsum[c] * invN;
        float var = bnsum[128 + c] * invN - mu * mu;
        float sc  = g[c] * rsqrtf(var + 1e-5f);
        float v = (h[i] - mu) * sc + b[c];
        h[i] = v;
        hb[i] = f2bf(v);
    }
}

// ---------------------------------------------------------------- dst count-sort + pack (once)
__global__ void k_hist(const int* __restrict__ edst, int* __restrict__ deg) {
    int e = blockIdx.x * 256 + threadIdx.x;
    if (e < N_EDGES) atomicAdd(&deg[edst[e]], 1);
}

#define SCAN_T 1024
#define CHUNK 49
__global__ void k_scan(const int* __restrict__ deg, int* __restrict__ row_ptr) {
    __shared__ int part[SCAN_T];
    int t = threadIdx.x;
    int begin = t * CHUNK;
    int end   = begin + CHUNK; if (end > N_NODES) end = N_NODES;
    int s = 0;
    for (int i = begin; i < end && i < N_NODES; ++i) s += deg[i];
    part[t] = s;
    __syncthreads();
    for (int off = 1; off < SCAN_T; off <<= 1) {
        int v = (t >= off) ? part[t - off] : 0;
        __syncthreads();
        part[t] += v;
        __syncthreads();
    }
    int run = (t == 0) ? 0 : part[t - 1];
    for (int i = begin; i < end && i < N_NODES; ++i) { row_ptr[i] = run; run += deg[i]; }
    if (t == SCAN_T - 1) row_ptr[N_NODES] = run;
}

__global__ void k_scatter(const int* __restrict__ edst, const int* __restrict__ row_ptr,
                          int* __restrict__ cnt, int* __restrict__ perm) {
    int e = blockIdx.x * 256 + threadIdx.x;
    if (e < N_EDGES) {
        int d = edst[e];
        int pos = row_ptr[d] + atomicAdd(&cnt[d], 1);
        perm[pos] = e;
    }
}

// pack sorted edge records: rmeta[i]=(src,dst), rea[i]=(ea0,ea1,ea2,env)
__global__ void k_pack(const int* __restrict__ perm, const int* __restrict__ esrc,
                       const int* __restrict__ edst, const float* __restrict__ ew,
                       const float* __restrict__ ea,
                       int2* __restrict__ rmeta, float4* __restrict__ rea) {
    int i = blockIdx.x * 256 + threadIdx.x;
    if (i < N_EDGES) {
        int e = perm[i];
        float w = ew[e];
        float env = 0.5f * (__cosf(w * 0.31415926535897932f) + 1.0f);
        rmeta[i] = make_int2(esrc[e], edst[e]);
        rea[i] = make_float4(ea[(size_t)e * 3], ea[(size_t)e * 3 + 1], ea[(size_t)e * 3 + 2], env);
    }
}

// ---------------------------------------------------------------- node GEMMs (bf16 MFMA)
// hin = hb(bf16) @ B + bias -> bf16
__global__ __launch_bounds__(256, 2) void k_ngemm_in(const unsigned short* __restrict__ hb,
                                                     const float* __restrict__ B,
                                                     const float* __restrict__ bias,
                                                     unsigned short* __restrict__ hinb) {
    __shared__ unsigned short WT[128 * WTP];
    __shared__ float bs[CDIM];
    for (int o = threadIdx.x; o < CDIM * CDIM; o += 256) {
        int k = o >> 7, c = o & 127;
        WT[c * WTP + k] = f2bf(B[o]);
    }
    if (threadIdx.x < CDIM) bs[threadIdx.x] = bias[threadIdx.x];
    __syncthreads();

    int lane = threadIdx.x & 63, wave = threadIdx.x >> 6;
    int m = lane & 15, q = lane >> 4;
    int rb = blockIdx.x * 64 + wave * 16;
    int row = rb + m;
    if (row > N_NODES - 1) row = N_NODES - 1;

    floatx4 acc[8];
#pragma unroll
    for (int nt = 0; nt < 8; ++nt) acc[nt] = (floatx4){0.f, 0.f, 0.f, 0.f};

#pragma unroll
    for (int kb = 0; kb < 4; ++kb) {
        int k0 = kb * 32 + q * 8;
        short8 af = *(const short8*)(hb + (size_t)row * CDIM + k0);   // 16B aligned
#pragma unroll
        for (int nt = 0; nt < 8; ++nt) {
            short8 bf = ldfrag(WT, nt * 16 + m, k0);
            acc[nt] = __builtin_amdgcn_mfma_f32_16x16x32_bf16(af, bf, acc[nt], 0, 0, 0);
        }
    }
#pragma unroll
    for (int nt = 0; nt < 8; ++nt) {
        int c = nt * 16 + m;
#pragma unroll
        for (int r = 0; r < 4; ++r) {
            int orow = rb + q * 4 + r;
            if (orow < N_NODES)
                hinb[(size_t)orow * CDIM + c] = f2bf(acc[nt][r] + bs[c]);
        }
    }
}

// h += ssp(agg@B + bias); writes hb shadow; ZERO: re-zero agg; POOL: atomicAdd into hg, no h write
template <int ZERO, int POOL>
__global__ __launch_bounds__(256, 2) void k_ngemm_out(float* __restrict__ agg,
                                                      const float* __restrict__ B,
                                                      const float* __restrict__ bias,
                                                      float* __restrict__ h,
                                                      unsigned short* __restrict__ hb,
                                                      const int* __restrict__ batch,
                                                      float* __restrict__ hg) {
    __shared__ unsigned short WT[128 * WTP];
    __shared__ float bs[CDIM];
    for (int o = threadIdx.x; o < CDIM * CDIM; o += 256) {
        int k = o >> 7, c = o & 127;
        WT[c * WTP + k] = f2bf(B[o]);
    }
    if (threadIdx.x < CDIM) bs[threadIdx.x] = bias[threadIdx.x];
    __syncthreads();

    int lane = threadIdx.x & 63, wave = threadIdx.x >> 6;
    int m = lane & 15, q = lane >> 4;
    int rb = blockIdx.x * 64 + wave * 16;
    int row = rb + m;
    if (row > N_NODES - 1) row = N_NODES - 1;

    floatx4 acc[8];
#pragma unroll
    for (int nt = 0; nt < 8; ++nt) acc[nt] = (floatx4){0.f, 0.f, 0.f, 0.f};

#pragma unroll
    for (int kb = 0; kb < 4; ++kb) {
        int k0 = kb * 32 + q * 8;
        const float* ap = agg + (size_t)row * CDIM + k0;
        float4 lo = *(const float4*)ap;
        float4 hi = *(const float4*)(ap + 4);
        short8 af;
        af[0] = (short)f2bf(lo.x); af[1] = (short)f2bf(lo.y);
        af[2] = (short)f2bf(lo.z); af[3] = (short)f2bf(lo.w);
        af[4] = (short)f2bf(hi.x); af[5] = (short)f2bf(hi.y);
        af[6] = (short)f2bf(hi.z); af[7] = (short)f2bf(hi.w);
#pragma unroll
        for (int nt = 0; nt < 8; ++nt) {
            short8 bf = ldfrag(WT, nt * 16 + m, k0);
            acc[nt] = __builtin_amdgcn_mfma_f32_16x16x32_bf16(af, bf, acc[nt], 0, 0, 0);
        }
    }

    int batchr[4];
    if (POOL) {
#pragma unroll
        for (int r = 0; r < 4; ++r) {
            int orow = rb + q * 4 + r;
            batchr[r] = (orow < N_NODES) ? batch[orow] : 0;
        }
    }
#pragma unroll
    for (int nt = 0; nt < 8; ++nt) {
        int c = nt * 16 + m;
#pragma unroll
        for (int r = 0; r < 4; ++r) {
            int orow = rb + q * 4 + r;
            if (orow < N_NODES) {
                size_t idx = (size_t)orow * CDIM + c;
                float hn = h[idx] + sspf(acc[nt][r] + bs[c]);
                if (POOL) {
                    atomicAdd(&hg[(size_t)batchr[r] * CDIM + c], hn);
                } else {
                    h[idx] = hn;
                    hb[idx] = f2bf(hn);
                }
                if (ZERO) agg[idx] = 0.f;
            }
        }
    }
}

// ---------------------------------------------------------------- fused edge kernel
// wave-private 16-edge tiles over dst-sorted packed records; no per-tile barriers.
__global__ __launch_bounds__(256, 4) void k_edge(
    const float* __restrict__ We1, const float* __restrict__ be1,
    const float* __restrict__ We2, const float* __restrict__ be2,
    const int2* __restrict__ rmeta, const float4* __restrict__ rea,
    const unsigned short* __restrict__ hin, float* __restrict__ agg) {
    __shared__ unsigned short WT[128 * WTP];
    __shared__ float we1s[3 * CDIM];
    __shared__ float be1s[CDIM];
    __shared__ float be2s[CDIM];

    for (int o = threadIdx.x; o < CDIM * CDIM; o += 256) {
        int k = o >> 7, c = o & 127;
        WT[c * WTP + k] = f2bf(We2[o]);
    }
    for (int o = threadIdx.x; o < 3 * CDIM; o += 256) we1s[o] = We1[o];
    if (threadIdx.x < CDIM) { be1s[threadIdx.x] = be1[threadIdx.x]; be2s[threadIdx.x] = be2[threadIdx.x]; }
    __syncthreads();   // the only barrier

    int lane = threadIdx.x & 63, wave = threadIdx.x >> 6;
    int m = lane & 15, q = lane >> 4;

    const int NT = N_EDGES / 16;                       // 50000 wave-tiles
    int nwaves = gridDim.x * 4;
    int wid = blockIdx.x * 4 + wave;
    int tpw = (NT + nwaves - 1) / nwaves;
    int t0 = wid * tpw;
    int t1 = t0 + tpw; if (t1 > NT) t1 = NT;
    if (t0 >= t1) return;

    const float* reaf = (const float*)rea;

    // metadata for first tile
    float4 eav; int2 sd[4]; float ev[4];
    {
        int s0 = t0 * 16;
        eav = rea[s0 + m];
#pragma unroll
        for (int r = 0; r < 4; ++r) {
            sd[r] = rmeta[s0 + q * 4 + r];
            ev[r] = reaf[(size_t)(s0 + q * 4 + r) * 4 + 3];
        }
    }

    for (int tile = t0; tile < t1; ++tile) {
        // ---- prefetch next tile's metadata
        float4 eav_n; int2 sd_n[4]; float ev_n[4];
        if (tile + 1 < t1) {
            int s0n = (tile + 1) * 16;
            eav_n = rea[s0n + m];
#pragma unroll
            for (int r = 0; r < 4; ++r) {
                sd_n[r] = rmeta[s0n + q * 4 + r];
                ev_n[r] = reaf[(size_t)(s0n + q * 4 + r) * 4 + 3];
            }
        }

        // ---- issue hin gathers early (overlap t-compute + MFMA)
        unsigned short hpre[4][8];
#pragma unroll
        for (int r = 0; r < 4; ++r) {
            const unsigned short* hp = hin + (size_t)sd[r].x * CDIM + m;
#pragma unroll
            for (int nt = 0; nt < 8; ++nt) hpre[r][nt] = hp[nt * 16];
        }

        // ---- t = ssp(ea@We1+be1) straight into A-frags: A[edge m][k=kb*32+q*8+j]
        float ea0 = eav.x, ea1 = eav.y, ea2 = eav.z;
        short8 af[4];
#pragma unroll
        for (int kb = 0; kb < 4; ++kb) {
#pragma unroll
            for (int jj = 0; jj < 4; ++jj) {
                int k = kb * 32 + q * 8 + jj * 2;
                float p0 = fmaf(we1s[k], ea0, fmaf(we1s[CDIM + k], ea1,
                             fmaf(we1s[2 * CDIM + k], ea2, be1s[k])));
                float p1 = fmaf(we1s[k + 1], ea0, fmaf(we1s[CDIM + k + 1], ea1,
                             fmaf(we1s[2 * CDIM + k + 1], ea2, be1s[k + 1])));
                unsigned int pk = (unsigned int)f2bf(sspf(p0)) |
                                  ((unsigned int)f2bf(sspf(p1)) << 16);
                ((unsigned int*)&af[kb])[jj] = pk;
            }
        }

        floatx4 acc[8];
#pragma unroll
        for (int nt = 0; nt < 8; ++nt) acc[nt] = (floatx4){0.f, 0.f, 0.f, 0.f};
#pragma unroll
        for (int kb = 0; kb < 4; ++kb)
#pragma unroll
            for (int nt = 0; nt < 8; ++nt) {
                short8 bf = ldfrag(WT, nt * 16 + m, kb * 32 + q * 8);
                acc[nt] = __builtin_amdgcn_mfma_f32_16x16x32_bf16(af[kb], bf, acc[nt], 0, 0, 0);
            }

        // ---- epilogue: run-merge over 4 consecutive dst-sorted edges
#pragma unroll
        for (int nt = 0; nt < 8; ++nt) {
            int c = nt * 16 + m;
            float bias = be2s[c];
            int cur = sd[0].y;
            float accv = (acc[nt][0] + bias) * ev[0] * bf2f(hpre[0][nt]);
#pragma unroll
            for (int r = 1; r < 4; ++r) {
                float msg = (acc[nt][r] + bias) * ev[r] * bf2f(hpre[r][nt]);
                if (sd[r].y != cur) {
                    atomicAdd(&agg[(size_t)cur * CDIM + c], accv);
                    cur = sd[r].y; accv = msg;
                } else {
                    accv += msg;
                }
            }
            atomicAdd(&agg[(size_t)cur * CDIM + c], accv);
        }

        eav = eav_n;
#pragma unroll
        for (int r = 0; r < 4; ++r) { sd[r] = sd_n[r]; ev[r] = ev_n[r]; }
    }
}

// ---------------------------------------------------------------- readout
__global__ void k_readout(const float* __restrict__ hg, const float* __restrict__ Wr1,
                          const float* __restrict__ br1, const float* __restrict__ Wr2,
                          const float* __restrict__ br2, float* __restrict__ out) {
    __shared__ float hgs[CDIM];
    int g = blockIdx.x;
    for (int o = threadIdx.x; o < CDIM; o += 64) hgs[o] = hg[(size_t)g * CDIM + o];
    __syncthreads();
    int c = threadIdx.x;
    float val = 0.f;
    if (c < 32) {
        float s = br1[c];
        for (int k = 0; k < CDIM; ++k) s += hgs[k] * Wr1[k * 32 + c];
        val = sspf(s) * Wr2[c];
    }
#pragma unroll
    for (int off = 16; off >= 1; off >>= 1) val += __shfl_down(val, off, 32);
    if (c == 0) out[g] = sspf(val + br2[0]);
}

// ---------------------------------------------------------------- launch
extern "C" void kernel_launch(void* const* d_in, const int* in_sizes, int n_in,
                              void* d_out, int out_size, void* d_ws, size_t ws_size,
                              hipStream_t stream) {
    const float* x     = (const float*)d_in[0];
    const int*   eidx  = (const int*)  d_in[1];
    const float* ew    = (const float*)d_in[2];
    const float* ea    = (const float*)d_in[3];
    const int*   batch = (const int*)  d_in[4];
    const float* Wl1   = (const float*)d_in[5];
    const float* bl1   = (const float*)d_in[6];
    const float* Wl2   = (const float*)d_in[7];
    const float* bl2   = (const float*)d_in[8];
    const float* bng   = (const float*)d_in[9];
    const float* bnb   = (const float*)d_in[10];
    const float* Wi_in = (const float*)d_in[11];
    const float* bi_in = (const float*)d_in[12];
    const float* We1   = (const float*)d_in[13];
    const float* be1   = (const float*)d_in[14];
    const float* We2   = (const float*)d_in[15];
    const float* be2   = (const float*)d_in[16];
    const float* Wi_o  = (const float*)d_in[17];
    const float* bi_o  = (const float*)d_in[18];
    const float* Wr1   = (const float*)d_in[19];
    const float* br1   = (const float*)d_in[20];
    const float* Wr2   = (const float*)d_in[21];
    const float* br2   = (const float*)d_in[22];
    float* out = (float*)d_out;

    float* ws  = (float*)d_ws;
    float*  h    = ws;                                          // 6.4M floats
    float*  agg  = h + (size_t)N_NODES * CDIM;                  // 6.4M floats
    float4* rea  = (float4*)(agg + (size_t)N_NODES * CDIM);     // E float4 (16B-aligned)
    float*  hg   = (float*)(rea + N_EDGES);                     // G*128
    float*  Wf   = hg + (size_t)N_GRAPH * CDIM;
    float*  bfv  = Wf + FINDIM * CDIM;
    float*  bnsum = bfv + CDIM;                                 // 256
    unsigned short* hb   = (unsigned short*)(bnsum + 256);      // N*128 bf16
    unsigned short* hinb = hb + (size_t)N_NODES * CDIM;         // N*128 bf16
    int2*  rmeta  = (int2*)(hinb + (size_t)N_NODES * CDIM);     // E int2
    int*   perm   = (int*)(rmeta + N_EDGES);                    // E
    int*   deg    = perm + N_EDGES;                             // N
    int*   row_ptr= deg + N_NODES;                              // N+1
    int*   cnt    = row_ptr + N_NODES + 1;                      // N

    const int* esrc = eidx;
    const int* edst = eidx + N_EDGES;

    // ---- sort by dst + pack records (reused by all 3 layers)
    hipMemsetAsync(deg, 0, (size_t)N_NODES * sizeof(int), stream);
    hipMemsetAsync(cnt, 0, (size_t)N_NODES * sizeof(int), stream);
    k_hist<<<(N_EDGES + 255) / 256, 256, 0, stream>>>(edst, deg);
    k_scan<<<1, SCAN_T, 0, stream>>>(deg, row_ptr);
    k_scatter<<<(N_EDGES + 255) / 256, 256, 0, stream>>>(edst, row_ptr, cnt, perm);
    k_pack<<<(N_EDGES + 255) / 256, 256, 0, stream>>>(perm, esrc, edst, ew, ea, rmeta, rea);

    // ---- embedding + BN
    hipMemsetAsync(bnsum, 0, 256 * sizeof(float), stream);
    k_fuse<<<1, 256, 0, stream>>>(Wl1, bl1, Wl2, bl2, Wf, bfv);
    k_embed_bn<<<512, 256, 0, stream>>>(x, Wf, bfv, h, bnsum);
    k_bnapply<<<1024, 256, 0, stream>>>(h, hb, bnsum, bng, bnb);

    // ---- interaction layers
    hipMemsetAsync(agg, 0, (size_t)N_NODES * CDIM * sizeof(float), stream);
    hipMemsetAsync(hg, 0, (size_t)N_GRAPH * CDIM * sizeof(float), stream);
    const int ngrid = (N_NODES + 63) / 64;
    for (int l = 0; l < NL; ++l) {
        k_ngemm_in<<<ngrid, 256, 0, stream>>>(hb, Wi_in + (size_t)l * CDIM * CDIM,
                                              bi_in + l * CDIM, hinb);
        k_edge<<<1024, 256, 0, stream>>>(We1 + l * 3 * CDIM, be1 + l * CDIM,
                                         We2 + (size_t)l * CDIM * CDIM, be2 + l * CDIM,
                                         rmeta, rea, hinb, agg);
        if (l < NL - 1)
            k_ngemm_out<1, 0><<<ngrid, 256, 0, stream>>>(agg, Wi_o + (size_t)l * CDIM * CDIM,
                                                         bi_o + l * CDIM, h, hb, batch, hg);
        else
            k_ngemm_out<0, 1><<<ngrid, 256, 0, stream>>>(agg, Wi_o + (size_t)l * CDIM * CDIM,
                                                         bi_o + l * CDIM, h, hb, batch, hg);
    }

    // ---- readout
    k_readout<<<N_GRAPH, 64, 0, stream>>>(hg, Wr1, br1, Wr2, br2, out);
}

// Round 6
// 946.612 us; speedup vs baseline: 2.8357x; 2.8357x over previous
//
#include <hip/hip_runtime.h>
#include <math.h>

#define N_NODES 50000
#define N_EDGES 800000
#define N_GRAPH 1024
#define CDIM 128
#define FINDIM 16
#define NL 3
#define WTP 132   // WT pitch (ushorts): b64 frag reads -> 4-way banks (1.58x), not 8-way

using short8  = __attribute__((ext_vector_type(8))) short;
using floatx4 = __attribute__((ext_vector_type(4))) float;

__device__ __forceinline__ float sspf(float x) {
    return fmaxf(x, 0.0f) + __logf(1.0f + __expf(-fabsf(x))) - 0.6931471805599453f;
}

__device__ __forceinline__ unsigned short f2bf(float f) {
    unsigned int u = __float_as_uint(f);
    u = u + 0x7FFFu + ((u >> 16) & 1u);   // RNE
    return (unsigned short)(u >> 16);
}

__device__ __forceinline__ float bf2f(unsigned short h) {
    return __uint_as_float((unsigned int)h << 16);
}

// B fragment from WT as 2x ds_read_b64 (8B aligned, 4-way banks)
__device__ __forceinline__ short8 ldfrag(const unsigned short* WT, int c, int k0) {
    const uint2* p = (const uint2*)(WT + c * WTP + k0);
    short8 r;
    *(uint2*)&r       = p[0];
    *((uint2*)&r + 1) = p[1];
    return r;
}

// ---------------------------------------------------------------- embedding (+ BN stats)
__global__ void k_fuse(const float* __restrict__ Wl1, const float* __restrict__ bl1,
                       const float* __restrict__ Wl2, const float* __restrict__ bl2,
                       float* __restrict__ Wf, float* __restrict__ bfv) {
    for (int o = threadIdx.x; o < FINDIM * CDIM + CDIM; o += 256) {
        if (o < FINDIM * CDIM) {
            int f = o >> 7, c = o & 127;
            float s = 0.f;
            for (int k = 0; k < CDIM; ++k) s += Wl1[f * CDIM + k] * Wl2[k * CDIM + c];
            Wf[o] = s;
        } else {
            int c = o - FINDIM * CDIM;
            float s = bl2[c];
            for (int k = 0; k < CDIM; ++k) s += bl1[k] * Wl2[k * CDIM + c];
            bfv[c] = s;
        }
    }
}

__global__ void k_embed_bn(const float* __restrict__ x, const float* __restrict__ Wf,
                           const float* __restrict__ bfv, float* __restrict__ h,
                           float* __restrict__ bnsum) {
    __shared__ float wfs[FINDIM * CDIM];
    __shared__ float bfs[CDIM];
    __shared__ float sd[512];
    for (int o = threadIdx.x; o < FINDIM * CDIM; o += 256) wfs[o] = Wf[o];
    if (threadIdx.x < CDIM) bfs[threadIdx.x] = bfv[threadIdx.x];
    __syncthreads();
    int c = threadIdx.x & 127;
    int half = threadIdx.x >> 7;
    float s1 = 0.f, s2 = 0.f;
    for (int base = blockIdx.x * 2; base < N_NODES; base += gridDim.x * 2) {
        int n = base + half;
        if (n < N_NODES) {
            float s = bfs[c];
            const float* xp = x + (size_t)n * FINDIM;
#pragma unroll
            for (int f = 0; f < FINDIM; ++f) s += xp[f] * wfs[f * CDIM + c];
            h[(size_t)n * CDIM + c] = s;
            s1 += s; s2 += s * s;
        }
    }
    sd[threadIdx.x] = s1; sd[256 + threadIdx.x] = s2;
    __syncthreads();
    if (threadIdx.x < 128) {
        atomicAdd(&bnsum[threadIdx.x], sd[threadIdx.x] + sd[threadIdx.x + 128]);
        atomicAdd(&bnsum[128 + threadIdx.x], sd[256 + threadIdx.x] + sd[256 + threadIdx.x + 128]);
    }
}

__global__ void k_bnapply(float* __restrict__ h, unsigned short* __restrict__ hb,
                          const float* __restrict__ bnsum,
                          const float* __restrict__ g, const float* __restrict__ b) {
    const float invN = 1.0f / (float)N_NODES;
    for (size_t i = (size_t)blockIdx.x * 256 + threadIdx.x; i < (size_t)N_NODES * CDIM;
         i += (size_t)gridDim.x * 256) {
        int c = (int)(i & 127);
        float mu  = bnsum[c] * invN;
        float var = bnsum[128 + c] * invN - mu * mu;
        float sc  = g[c] * rsqrtf(var + 1e-5f);
        float v = (h[i] - mu) * sc + b[c];
        h[i] = v;
        hb[i] = f2bf(v);
    }
}

// ---------------------------------------------------------------- dst count-sort + pack (once)
__global__ void k_hist(const int* __restrict__ edst, int* __restrict__ deg) {
    int e = blockIdx.x * 256 + threadIdx.x;
    if (e < N_EDGES) atomicAdd(&deg[edst[e]], 1);
}

#define SCAN_T 1024
#define CHUNK 49
__global__ void k_scan(const int* __restrict__ deg, int* __restrict__ row_ptr) {
    __shared__ int part[SCAN_T];
    int t = threadIdx.x;
    int begin = t * CHUNK;
    int end   = begin + CHUNK; if (end > N_NODES) end = N_NODES;
    int s = 0;
    for (int i = begin; i < end && i < N_NODES; ++i) s += deg[i];
    part[t] = s;
    __syncthreads();
    for (int off = 1; off < SCAN_T; off <<= 1) {
        int v = (t >= off) ? part[t - off] : 0;
        __syncthreads();
        part[t] += v;
        __syncthreads();
    }
    int run = (t == 0) ? 0 : part[t - 1];
    for (int i = begin; i < end && i < N_NODES; ++i) { row_ptr[i] = run; run += deg[i]; }
    if (t == SCAN_T - 1) row_ptr[N_NODES] = run;
}

__global__ void k_scatter(const int* __restrict__ edst, const int* __restrict__ row_ptr,
                          int* __restrict__ cnt, int* __restrict__ perm) {
    int e = blockIdx.x * 256 + threadIdx.x;
    if (e < N_EDGES) {
        int d = edst[e];
        int pos = row_ptr[d] + atomicAdd(&cnt[d], 1);
        perm[pos] = e;
    }
}

__global__ void k_pack(const int* __restrict__ perm, const int* __restrict__ esrc,
                       const int* __restrict__ edst, const float* __restrict__ ew,
                       const float* __restrict__ ea,
                       int2* __restrict__ rmeta, float4* __restrict__ rea) {
    int i = blockIdx.x * 256 + threadIdx.x;
    if (i < N_EDGES) {
        int e = perm[i];
        float w = ew[e];
        float env = 0.5f * (__cosf(w * 0.31415926535897932f) + 1.0f);
        rmeta[i] = make_int2(esrc[e], edst[e]);
        rea[i] = make_float4(ea[(size_t)e * 3], ea[(size_t)e * 3 + 1], ea[(size_t)e * 3 + 2], env);
    }
}

// ---------------------------------------------------------------- node GEMMs (bf16 MFMA)
__global__ __launch_bounds__(256, 2) void k_ngemm_in(const unsigned short* __restrict__ hb,
                                                     const float* __restrict__ B,
                                                     const float* __restrict__ bias,
                                                     unsigned short* __restrict__ hinb) {
    __shared__ unsigned short WT[128 * WTP];
    __shared__ float bs[CDIM];
    for (int o = threadIdx.x; o < CDIM * CDIM; o += 256) {
        int k = o >> 7, c = o & 127;
        WT[c * WTP + k] = f2bf(B[o]);
    }
    if (threadIdx.x < CDIM) bs[threadIdx.x] = bias[threadIdx.x];
    __syncthreads();

    int lane = threadIdx.x & 63, wave = threadIdx.x >> 6;
    int m = lane & 15, q = lane >> 4;
    int rb = blockIdx.x * 64 + wave * 16;
    int row = rb + m;
    if (row > N_NODES - 1) row = N_NODES - 1;

    floatx4 acc[8];
#pragma unroll
    for (int nt = 0; nt < 8; ++nt) acc[nt] = (floatx4){0.f, 0.f, 0.f, 0.f};

#pragma unroll
    for (int kb = 0; kb < 4; ++kb) {
        int k0 = kb * 32 + q * 8;
        short8 af = *(const short8*)(hb + (size_t)row * CDIM + k0);
#pragma unroll
        for (int nt = 0; nt < 8; ++nt) {
            short8 bf = ldfrag(WT, nt * 16 + m, k0);
            acc[nt] = __builtin_amdgcn_mfma_f32_16x16x32_bf16(af, bf, acc[nt], 0, 0, 0);
        }
    }
#pragma unroll
    for (int nt = 0; nt < 8; ++nt) {
        int c = nt * 16 + m;
#pragma unroll
        for (int r = 0; r < 4; ++r) {
            int orow = rb + q * 4 + r;
            if (orow < N_NODES)
                hinb[(size_t)orow * CDIM + c] = f2bf(acc[nt][r] + bs[c]);
        }
    }
}

template <int ZERO, int POOL>
__global__ __launch_bounds__(256, 2) void k_ngemm_out(float* __restrict__ agg,
                                                      const float* __restrict__ B,
                                                      const float* __restrict__ bias,
                                                      float* __restrict__ h,
                                                      unsigned short* __restrict__ hb,
                                                      const int* __restrict__ batch,
                                                      float* __restrict__ hg) {
    __shared__ unsigned short WT[128 * WTP];
    __shared__ float bs[CDIM];
    for (int o = threadIdx.x; o < CDIM * CDIM; o += 256) {
        int k = o >> 7, c = o & 127;
        WT[c * WTP + k] = f2bf(B[o]);
    }
    if (threadIdx.x < CDIM) bs[threadIdx.x] = bias[threadIdx.x];
    __syncthreads();

    int lane = threadIdx.x & 63, wave = threadIdx.x >> 6;
    int m = lane & 15, q = lane >> 4;
    int rb = blockIdx.x * 64 + wave * 16;
    int row = rb + m;
    if (row > N_NODES - 1) row = N_NODES - 1;

    floatx4 acc[8];
#pragma unroll
    for (int nt = 0; nt < 8; ++nt) acc[nt] = (floatx4){0.f, 0.f, 0.f, 0.f};

#pragma unroll
    for (int kb = 0; kb < 4; ++kb) {
        int k0 = kb * 32 + q * 8;
        const float* ap = agg + (size_t)row * CDIM + k0;
        float4 lo = *(const float4*)ap;
        float4 hi = *(const float4*)(ap + 4);
        short8 af;
        af[0] = (short)f2bf(lo.x); af[1] = (short)f2bf(lo.y);
        af[2] = (short)f2bf(lo.z); af[3] = (short)f2bf(lo.w);
        af[4] = (short)f2bf(hi.x); af[5] = (short)f2bf(hi.y);
        af[6] = (short)f2bf(hi.z); af[7] = (short)f2bf(hi.w);
#pragma unroll
        for (int nt = 0; nt < 8; ++nt) {
            short8 bf = ldfrag(WT, nt * 16 + m, k0);
            acc[nt] = __builtin_amdgcn_mfma_f32_16x16x32_bf16(af, bf, acc[nt], 0, 0, 0);
        }
    }

    int batchr[4];
    if (POOL) {
#pragma unroll
        for (int r = 0; r < 4; ++r) {
            int orow = rb + q * 4 + r;
            batchr[r] = (orow < N_NODES) ? batch[orow] : 0;
        }
    }
#pragma unroll
    for (int nt = 0; nt < 8; ++nt) {
        int c = nt * 16 + m;
#pragma unroll
        for (int r = 0; r < 4; ++r) {
            int orow = rb + q * 4 + r;
            if (orow < N_NODES) {
                size_t idx = (size_t)orow * CDIM + c;
                float hn = h[idx] + sspf(acc[nt][r] + bs[c]);
                if (POOL) {
                    atomicAdd(&hg[(size_t)batchr[r] * CDIM + c], hn);
                } else {
                    h[idx] = hn;
                    hb[idx] = f2bf(hn);
                }
                if (ZERO) agg[idx] = 0.f;
            }
        }
    }
}

// ---------------------------------------------------------------- fused edge kernel
// R4 block-lockstep 64-edge tiles (L2-friendly) + WTP=132 b64 frags (bank fix)
// + cross-lane (^16,^32) dst merge to cut atomic ops ~4-5x.
__global__ __launch_bounds__(256, 4) void k_edge(
    const float* __restrict__ We1, const float* __restrict__ be1,
    const float* __restrict__ We2, const float* __restrict__ be2,
    const int2* __restrict__ rmeta, const float4* __restrict__ rea,
    const unsigned short* __restrict__ hin, float* __restrict__ agg) {
    __shared__ unsigned short WT[128 * WTP];
    __shared__ float we1s[3 * CDIM];
    __shared__ float be1s[CDIM];
    __shared__ float be2s[CDIM];
    __shared__ int2   sds[64];
    __shared__ float4 eas4[64];

    for (int o = threadIdx.x; o < CDIM * CDIM; o += 256) {
        int k = o >> 7, c = o & 127;
        WT[c * WTP + k] = f2bf(We2[o]);
    }
    for (int o = threadIdx.x; o < 3 * CDIM; o += 256) we1s[o] = We1[o];
    if (threadIdx.x < CDIM) { be1s[threadIdx.x] = be1[threadIdx.x]; be2s[threadIdx.x] = be2[threadIdx.x]; }
    __syncthreads();

    int lane = threadIdx.x & 63, wave = threadIdx.x >> 6;
    int m = lane & 15, q = lane >> 4;

    const int ntiles = N_EDGES / 64;
    int tpb = (ntiles + gridDim.x - 1) / gridDim.x;
    int t0 = blockIdx.x * tpb;
    int t1 = t0 + tpb; if (t1 > ntiles) t1 = ntiles;

    for (int tile = t0; tile < t1; ++tile) {
        int s0 = tile * 64;
        __syncthreads();   // previous tile's readers done
        if (threadIdx.x < 64)       sds[threadIdx.x]        = rmeta[s0 + threadIdx.x];
        else if (threadIdx.x < 128) eas4[threadIdx.x - 64]  = rea[s0 + threadIdx.x - 64];
        __syncthreads();

        // per-thread edge metadata (regs) — frees LDS for next-iter staging
        int el0 = wave * 16 + q * 4;
        int2 sd[4]; float ev[4];
#pragma unroll
        for (int r = 0; r < 4; ++r) { sd[r] = sds[el0 + r]; ev[r] = eas4[el0 + r].w; }

        // ---- issue hin gathers early (overlap t-compute + MFMA)
        unsigned short hpre[4][8];
#pragma unroll
        for (int r = 0; r < 4; ++r) {
            const unsigned short* hp = hin + (size_t)sd[r].x * CDIM + m;
#pragma unroll
            for (int nt = 0; nt < 8; ++nt) hpre[r][nt] = hp[nt * 16];
        }

        // ---- t = ssp(ea@We1+be1) straight into A-frags
        float4 eav = eas4[wave * 16 + m];
        float ea0 = eav.x, ea1 = eav.y, ea2 = eav.z;
        short8 af[4];
#pragma unroll
        for (int kb = 0; kb < 4; ++kb) {
#pragma unroll
            for (int jj = 0; jj < 4; ++jj) {
                int k = kb * 32 + q * 8 + jj * 2;
                float p0 = fmaf(we1s[k], ea0, fmaf(we1s[CDIM + k], ea1,
                             fmaf(we1s[2 * CDIM + k], ea2, be1s[k])));
                float p1 = fmaf(we1s[k + 1], ea0, fmaf(we1s[CDIM + k + 1], ea1,
                             fmaf(we1s[2 * CDIM + k + 1], ea2, be1s[k + 1])));
                unsigned int pk = (unsigned int)f2bf(sspf(p0)) |
                                  ((unsigned int)f2bf(sspf(p1)) << 16);
                ((unsigned int*)&af[kb])[jj] = pk;
            }
        }

        floatx4 acc[8];
#pragma unroll
        for (int nt = 0; nt < 8; ++nt) acc[nt] = (floatx4){0.f, 0.f, 0.f, 0.f};
#pragma unroll
        for (int kb = 0; kb < 4; ++kb)
#pragma unroll
            for (int nt = 0; nt < 8; ++nt) {
                short8 bf = ldfrag(WT, nt * 16 + m, kb * 32 + q * 8);
                acc[nt] = __builtin_amdgcn_mfma_f32_16x16x32_bf16(af[kb], bf, acc[nt], 0, 0, 0);
            }

        // ---- epilogue
        bool uni = (sd[0].y == sd[3].y);   // uniform per 16-lane q-group
        float vv[8];
#pragma unroll
        for (int nt = 0; nt < 8; ++nt) {
            float bias = be2s[nt * 16 + m];
            float s = 0.f;
#pragma unroll
            for (int r = 0; r < 4; ++r)
                s += (acc[nt][r] + bias) * ev[r] * bf2f(hpre[r][nt]);
            vv[nt] = s;
        }

        // cross-lane merge over q (^16 then ^32); all 64 lanes participate
        int owner = uni ? 1 : 0;
        int myd   = uni ? sd[0].y : -1 - lane;   // unique sentinel when not mergeable
#pragma unroll
        for (int s = 16; s <= 32; s <<= 1) {
            int od = __shfl_xor(myd, s, 64);
            int oo = __shfl_xor(owner, s, 64);
            bool match = owner && oo && (od == myd);
            bool lower = ((lane & s) == 0);
#pragma unroll
            for (int nt = 0; nt < 8; ++nt) {
                float ovv = __shfl_xor(vv[nt], s, 64);
                if (match && lower) vv[nt] += ovv;
            }
            if (match && !lower) { owner = 0; myd = -1 - lane; }
        }

        if (uni) {
            if (owner) {
                float* ap = agg + (size_t)myd * CDIM + m;
#pragma unroll
                for (int nt = 0; nt < 8; ++nt) atomicAdd(&ap[nt * 16], vv[nt]);
            }
        } else {
            // fallback: per-thread run-merge over the 4 sorted edges
#pragma unroll
            for (int nt = 0; nt < 8; ++nt) {
                int c = nt * 16 + m;
                float bias = be2s[c];
                int cur = sd[0].y;
                float accv = (acc[nt][0] + bias) * ev[0] * bf2f(hpre[0][nt]);
#pragma unroll
                for (int r = 1; r < 4; ++r) {
                    float msg = (acc[nt][r] + bias) * ev[r] * bf2f(hpre[r][nt]);
                    if (sd[r].y != cur) {
                        atomicAdd(&agg[(size_t)cur * CDIM + c], accv);
                        cur = sd[r].y; accv = msg;
                    } else {
                        accv += msg;
                    }
                }
                atomicAdd(&agg[(size_t)cur * CDIM + c], accv);
            }
        }
    }
}

// ---------------------------------------------------------------- readout
__global__ void k_readout(const float* __restrict__ hg, const float* __restrict__ Wr1,
                          const float* __restrict__ br1, const float* __restrict__ Wr2,
                          const float* __restrict__ br2, float* __restrict__ out) {
    __shared__ float hgs[CDIM];
    int g = blockIdx.x;
    for (int o = threadIdx.x; o < CDIM; o += 64) hgs[o] = hg[(size_t)g * CDIM + o];
    __syncthreads();
    int c = threadIdx.x;
    float val = 0.f;
    if (c < 32) {
        float s = br1[c];
        for (int k = 0; k < CDIM; ++k) s += hgs[k] * Wr1[k * 32 + c];
        val = sspf(s) * Wr2[c];
    }
#pragma unroll
    for (int off = 16; off >= 1; off >>= 1) val += __shfl_down(val, off, 32);
    if (c == 0) out[g] = sspf(val + br2[0]);
}

// ---------------------------------------------------------------- launch
extern "C" void kernel_launch(void* const* d_in, const int* in_sizes, int n_in,
                              void* d_out, int out_size, void* d_ws, size_t ws_size,
                              hipStream_t stream) {
    const float* x     = (const float*)d_in[0];
    const int*   eidx  = (const int*)  d_in[1];
    const float* ew    = (const float*)d_in[2];
    const float* ea    = (const float*)d_in[3];
    const int*   batch = (const int*)  d_in[4];
    const float* Wl1   = (const float*)d_in[5];
    const float* bl1   = (const float*)d_in[6];
    const float* Wl2   = (const float*)d_in[7];
    const float* bl2   = (const float*)d_in[8];
    const float* bng   = (const float*)d_in[9];
    const float* bnb   = (const float*)d_in[10];
    const float* Wi_in = (const float*)d_in[11];
    const float* bi_in = (const float*)d_in[12];
    const float* We1   = (const float*)d_in[13];
    const float* be1   = (const float*)d_in[14];
    const float* We2   = (const float*)d_in[15];
    const float* be2   = (const float*)d_in[16];
    const float* Wi_o  = (const float*)d_in[17];
    const float* bi_o  = (const float*)d_in[18];
    const float* Wr1   = (const float*)d_in[19];
    const float* br1   = (const float*)d_in[20];
    const float* Wr2   = (const float*)d_in[21];
    const float* br2   = (const float*)d_in[22];
    float* out = (float*)d_out;

    float* ws  = (float*)d_ws;
    float*  h    = ws;                                          // N*128 f32
    float*  agg  = h + (size_t)N_NODES * CDIM;                  // N*128 f32
    float4* rea  = (float4*)(agg + (size_t)N_NODES * CDIM);     // E float4
    float*  hg   = (float*)(rea + N_EDGES);                     // G*128
    float*  Wf   = hg + (size_t)N_GRAPH * CDIM;
    float*  bfv  = Wf + FINDIM * CDIM;
    float*  bnsum = bfv + CDIM;                                 // 256
    unsigned short* hb   = (unsigned short*)(bnsum + 256);      // N*128 bf16
    unsigned short* hinb = hb + (size_t)N_NODES * CDIM;         // N*128 bf16
    int2*  rmeta  = (int2*)(hinb + (size_t)N_NODES * CDIM);     // E int2
    int*   perm   = (int*)(rmeta + N_EDGES);                    // E
    int*   deg    = perm + N_EDGES;                             // N
    int*   row_ptr= deg + N_NODES;                              // N+1
    int*   cnt    = row_ptr + N_NODES + 1;                      // N

    const int* esrc = eidx;
    const int* edst = eidx + N_EDGES;

    // ---- sort by dst + pack records (reused by all 3 layers)
    hipMemsetAsync(deg, 0, (size_t)N_NODES * sizeof(int), stream);
    hipMemsetAsync(cnt, 0, (size_t)N_NODES * sizeof(int), stream);
    k_hist<<<(N_EDGES + 255) / 256, 256, 0, stream>>>(edst, deg);
    k_scan<<<1, SCAN_T, 0, stream>>>(deg, row_ptr);
    k_scatter<<<(N_EDGES + 255) / 256, 256, 0, stream>>>(edst, row_ptr, cnt, perm);
    k_pack<<<(N_EDGES + 255) / 256, 256, 0, stream>>>(perm, esrc, edst, ew, ea, rmeta, rea);

    // ---- embedding + BN
    hipMemsetAsync(bnsum, 0, 256 * sizeof(float), stream);
    k_fuse<<<1, 256, 0, stream>>>(Wl1, bl1, Wl2, bl2, Wf, bfv);
    k_embed_bn<<<512, 256, 0, stream>>>(x, Wf, bfv, h, bnsum);
    k_bnapply<<<1024, 256, 0, stream>>>(h, hb, bnsum, bng, bnb);

    // ---- interaction layers
    hipMemsetAsync(agg, 0, (size_t)N_NODES * CDIM * sizeof(float), stream);
    hipMemsetAsync(hg, 0, (size_t)N_GRAPH * CDIM * sizeof(float), stream);
    const int ngrid = (N_NODES + 63) / 64;
    for (int l = 0; l < NL; ++l) {
        k_ngemm_in<<<ngrid, 256, 0, stream>>>(hb, Wi_in + (size_t)l * CDIM * CDIM,
                                              bi_in + l * CDIM, hinb);
        k_edge<<<1024, 256, 0, stream>>>(We1 + l * 3 * CDIM, be1 + l * CDIM,
                                         We2 + (size_t)l * CDIM * CDIM, be2 + l * CDIM,
                                         rmeta, rea, hinb, agg);
        if (l < NL - 1)
            k_ngemm_out<1, 0><<<ngrid, 256, 0, stream>>>(agg, Wi_o + (size_t)l * CDIM * CDIM,
                                                         bi_o + l * CDIM, h, hb, batch, hg);
        else
            k_ngemm_out<0, 1><<<ngrid, 256, 0, stream>>>(agg, Wi_o + (size_t)l * CDIM * CDIM,
                                                         bi_o + l * CDIM, h, hb, batch, hg);
    }

    // ---- readout
    k_readout<<<N_GRAPH, 64, 0, stream>>>(hg, Wr1, br1, Wr2, br2, out);
}